// Round 1
// 351.251 us; speedup vs baseline: 1.0560x; 1.0560x over previous
//
#include <hip/hip_runtime.h>
#include <hip/hip_bf16.h>
#include <math.h>

#define B_ 16
#define N_ 1024
#define T_ 12
#define DM_ 512
#define H_ 3
#define K_ 3
#define C_ 32
#define RSQRT_DK 0.17677669529663687f

typedef __attribute__((ext_vector_type(8))) short bf16x8;
typedef __attribute__((ext_vector_type(4))) float f32x4;

__device__ __forceinline__ ushort f2bf(float f) {   // RNE float->bf16 bits
  uint u = __float_as_uint(f);
  return (ushort)((u + 0x7FFF + ((u >> 16) & 1)) >> 16);
}

// ---------------- K1: temporal embedding LayerNorm over N ----------------
__global__ void k1_temporal_ln(const float* __restrict__ x, const float* __restrict__ posT,
                               const float* __restrict__ gT, const float* __restrict__ bT,
                               float* __restrict__ TEmx) {
  int row = blockIdx.x;                 // b*T + t
  int b = row / T_, t = row - b * T_;
  __shared__ float red[256], red2[256];
  float v[4]; float s = 0.f, s2 = 0.f;
  for (int i = 0; i < 4; ++i) {
    int n = threadIdx.x + (i << 8);
    float val = x[(b * N_ + n) * T_ + t] + posT[t * N_ + n];
    v[i] = val; s += val; s2 += val * val;
  }
  red[threadIdx.x] = s; red2[threadIdx.x] = s2;
  __syncthreads();
  for (int off = 128; off > 0; off >>= 1) {
    if (threadIdx.x < off) { red[threadIdx.x] += red[threadIdx.x + off]; red2[threadIdx.x] += red2[threadIdx.x + off]; }
    __syncthreads();
  }
  float mu = red[0] * (1.f / N_);
  float rs = rsqrtf(red2[0] * (1.f / N_) - mu * mu + 1e-5f);
  for (int i = 0; i < 4; ++i) {
    int n = threadIdx.x + (i << 8);
    TEmx[row * N_ + n] = (v[i] - mu) * rs * gT[n] + bT[n];
  }
}

// ---------------- K2 v2: temporal Q/K/V projections, K-split x4 ----------------
__global__ __launch_bounds__(256) void k2_qkv(const float* __restrict__ TEmx,
                       const float* __restrict__ WQ, const float* __restrict__ WK,
                       const float* __restrict__ WV, float* __restrict__ part) {
  int kc = blockIdx.x, row = blockIdx.y;
  __shared__ float e[256];
  int tid = threadIdx.x;
  e[tid] = TEmx[row * N_ + kc * 256 + tid];
  __syncthreads();
  for (int col = tid; col < 288; col += 256) {
    int which = col / 96, j = col - which * 96;
    const float* W = (which == 0) ? WQ : ((which == 1) ? WK : WV);
    const float* Wp = W + (size_t)(kc * 256) * 96 + j;
    float acc = 0.f;
    #pragma unroll 8
    for (int n = 0; n < 256; ++n) acc += e[n] * Wp[n * 96];
    part[(row * 4 + kc) * 288 + col] = acc;
  }
}

// ---------------- K3a: temporal attention (sums k2 partials during staging) ----------------
__global__ void k3a_attn(const float* __restrict__ part, const float* __restrict__ res_att,
                         float* __restrict__ reAt_out, float* __restrict__ ctx) {
  int b = blockIdx.x;
  __shared__ float q_l[T_ * 288];
  __shared__ float s_l[H_ * T_ * T_];
  for (int i = threadIdx.x; i < T_ * 288; i += 256) {
    int t = i / 288, col = i - t * 288;
    const float* pr = &part[(size_t)((b * T_ + t) * 4) * 288 + col];
    q_l[i] = pr[0] + pr[288] + pr[576] + pr[864];
  }
  __syncthreads();
  for (int idx = threadIdx.x; idx < H_ * T_ * T_; idx += 256) {
    int h = idx / 144, r = idx - h * 144, qi = r / 12, ki = r - qi * 12;
    float acc = 0.f;
    #pragma unroll
    for (int d = 0; d < 32; ++d)
      acc += q_l[qi * 288 + h * 32 + d] * q_l[ki * 288 + 96 + h * 32 + d];
    float sv = acc * RSQRT_DK + res_att[(b * H_ + h) * 144 + qi * 12 + ki];
    s_l[idx] = sv;
    reAt_out[(b * H_ + h) * 144 + qi * 12 + ki] = sv;
  }
  __syncthreads();
  if (threadIdx.x < 36) {
    int h = threadIdx.x / 12, qi = threadIdx.x - h * 12;
    float mx = -1e30f;
    for (int ki = 0; ki < 12; ++ki) mx = fmaxf(mx, s_l[h * 144 + qi * 12 + ki]);
    float sum = 0.f;
    for (int ki = 0; ki < 12; ++ki) { float p = __expf(s_l[h * 144 + qi * 12 + ki] - mx); s_l[h * 144 + qi * 12 + ki] = p; sum += p; }
    float inv = 1.f / sum;
    for (int ki = 0; ki < 12; ++ki) s_l[h * 144 + qi * 12 + ki] *= inv;
  }
  __syncthreads();
  for (int idx = threadIdx.x; idx < T_ * 96; idx += 256) {
    int qi = idx / 96, hd = idx - qi * 96, h = hd >> 5, d = hd & 31;
    float acc = 0.f;
    for (int ki = 0; ki < 12; ++ki)
      acc += s_l[h * 144 + qi * 12 + ki] * q_l[ki * 288 + 192 + h * 32 + d];
    ctx[(b * T_ + qi) * 96 + hd] = acc;
  }
}

// ---------------- K3b v2: ctx @ fc_t + TEmx, LayerNorm; 1024 thr, 1 n/thread ----------------
__global__ __launch_bounds__(1024) void k3b_tat(const float* __restrict__ ctx,
                        const float* __restrict__ fc_t,
                        const float* __restrict__ TEmx, float* __restrict__ TAT) {
  int row = blockIdx.x;
  __shared__ float c_l[96];
  __shared__ float red[16], red2[16];
  int tid = threadIdx.x;
  if (tid < 96) c_l[tid] = ctx[row * 96 + tid];
  __syncthreads();
  float acc = TEmx[row * N_ + tid];
  #pragma unroll 12
  for (int j = 0; j < 96; ++j) acc = fmaf(c_l[j], fc_t[j * N_ + tid], acc);
  float s = acc, s2 = acc * acc;
  #pragma unroll
  for (int off = 32; off > 0; off >>= 1) {
    s  += __shfl_xor(s, off);
    s2 += __shfl_xor(s2, off);
  }
  int w = tid >> 6;
  if ((tid & 63) == 0) { red[w] = s; red2[w] = s2; }
  __syncthreads();
  float ts = 0.f, ts2 = 0.f;
  #pragma unroll
  for (int i = 0; i < 16; ++i) { ts += red[i]; ts2 += red2[i]; }
  float mu = ts * (1.f / N_);
  float rs = rsqrtf(ts2 * (1.f / N_) - mu * mu + 1e-5f);
  TAT[row * N_ + tid] = (acc - mu) * rs;
}

// ---------------- K4: pre_conv + pos_embed_S + LayerNorm over 512 ----------------
__global__ void k4_preconv_ln(const float* __restrict__ TAT, const float* __restrict__ pcw,
                              const float* __restrict__ pcb, const float* __restrict__ posS,
                              const float* __restrict__ gS, const float* __restrict__ bS,
                              float* __restrict__ SEmx) {
  int bn = blockIdx.x; int b = bn >> 10, n = bn & 1023;
  __shared__ float tc[12];
  __shared__ float red[256], red2[256];
  if (threadIdx.x < 12) tc[threadIdx.x] = TAT[(b * T_ + threadIdx.x) * N_ + n];
  __syncthreads();
  float v[2]; float s = 0.f, s2 = 0.f;
  for (int i = 0; i < 2; ++i) {
    int d = threadIdx.x + (i << 8);
    float acc = pcb[d];
    #pragma unroll
    for (int t = 0; t < 12; ++t) acc += tc[t] * pcw[d * 12 + t];
    acc += posS[n * DM_ + d];
    v[i] = acc; s += acc; s2 += acc * acc;
  }
  red[threadIdx.x] = s; red2[threadIdx.x] = s2;
  __syncthreads();
  for (int off = 128; off > 0; off >>= 1) {
    if (threadIdx.x < off) { red[threadIdx.x] += red[threadIdx.x + off]; red2[threadIdx.x] += red2[threadIdx.x + off]; }
    __syncthreads();
  }
  float mu = red[0] * (1.f / DM_);
  float rs = rsqrtf(red2[0] * (1.f / DM_) - mu * mu + 1e-5f);
  for (int i = 0; i < 2; ++i) {
    int d = threadIdx.x + (i << 8);
    SEmx[bn * DM_ + d] = (v[i] - mu) * rs * gS[d] + bS[d];
  }
}

// ---------------- K5pre: [WQs|WKs] -> bf16 wpre[col][512] ----------------
__global__ void k5_pre(const float* __restrict__ WQs, const float* __restrict__ WKs,
                       ushort* __restrict__ wpre) {
  int idx = blockIdx.x * 256 + threadIdx.x;   // over 512*192
  int k = idx / 192, col = idx - k * 192;
  float v = (col < 96) ? WQs[k * 96 + col] : WKs[k * 96 + (col - 96)];
  wpre[col * 512 + k] = f2bf(v);
}

// ---------------- K5 v5: spatial Q/K projections as bf16 MFMA GEMM ----------------
// C[col=m][node=n] = sum_d W[d][col]*SE[node][d]; A=wpre[col][512], B=SE_h[node][520]
__global__ __launch_bounds__(256) void k5_qks(const float* __restrict__ SEmx,
                                              const ushort* __restrict__ wpre,
                                              __hip_bfloat16* __restrict__ Qs,
                                              __hip_bfloat16* __restrict__ Ks) {
  int b = blockIdx.y, n0 = blockIdx.x * 32;
  __shared__ __align__(16) ushort SE_h[32 * 520];   // [node][k], pad 8 -> 2-way free
  int tid = threadIdx.x;
  // stage SE tile f32 -> bf16: 16384 elems, 4/iter/thread
  for (int idx = tid; idx < 4096; idx += 256) {
    int r = idx >> 7, cq = idx & 127;
    float4 v = *(const float4*)&SEmx[((size_t)((b << 10) + n0 + r)) * DM_ + cq * 4];
    uint lo = (uint)f2bf(v.x) | ((uint)f2bf(v.y) << 16);
    uint hi = (uint)f2bf(v.z) | ((uint)f2bf(v.w) << 16);
    *(uint2*)&SE_h[r * 520 + cq * 4] = make_uint2(lo, hi);
  }
  __syncthreads();

  int w = tid >> 6, lane = tid & 63, quad = lane >> 4, c16 = lane & 15;
  f32x4 acc[3][2];
  #pragma unroll
  for (int mi = 0; mi < 3; ++mi)
    #pragma unroll
    for (int nt = 0; nt < 2; ++nt) acc[mi][nt] = (f32x4){0.f, 0.f, 0.f, 0.f};

  for (int ks = 0; ks < 16; ++ks) {
    bf16x8 Bf0 = *(const bf16x8*)&SE_h[(0 * 16 + c16) * 520 + ks * 32 + quad * 8];
    bf16x8 Bf1 = *(const bf16x8*)&SE_h[(1 * 16 + c16) * 520 + ks * 32 + quad * 8];
    #pragma unroll
    for (int mi = 0; mi < 3; ++mi) {
      int m = (w * 3 + mi) * 16 + c16;
      bf16x8 Af = *(const bf16x8*)&wpre[m * 512 + ks * 32 + quad * 8];
      acc[mi][0] = __builtin_amdgcn_mfma_f32_16x16x32_bf16(Af, Bf0, acc[mi][0], 0, 0, 0);
      acc[mi][1] = __builtin_amdgcn_mfma_f32_16x16x32_bf16(Af, Bf1, acc[mi][1], 0, 0, 0);
    }
  }
  #pragma unroll
  for (int mi = 0; mi < 3; ++mi) {
    int mb = (w * 3 + mi) * 16;
    #pragma unroll
    for (int nt = 0; nt < 2; ++nt) {
      int node = n0 + nt * 16 + c16;
      #pragma unroll
      for (int r = 0; r < 4; ++r) {
        int m = mb + quad * 4 + r;                 // 0..191
        int j = (m < 96) ? m : m - 96;
        int kk = j >> 5, dd = j & 31;
        __hip_bfloat16* o = (m < 96) ? Qs : Ks;
        o[(((b * K_ + kk) * N_) + node) * 32 + dd] = __float2bfloat16(acc[mi][nt][r]);
      }
    }
  }
}

// ---------------- K6pre v2: pack {adj*mask, cheb} as 2xbf16 in uint ----------------
__global__ void k6_pre(const float* __restrict__ adj, const float* __restrict__ mask,
                       const float* __restrict__ cheb, uint* __restrict__ pk) {
  int idx = blockIdx.x * 256 + threadIdx.x;     // over 3*1024*1024
  int mn = idx & (N_ * N_ - 1);
  uint lo = f2bf(adj[mn] * mask[idx]);
  uint hi = f2bf(cheb[idx]);
  pk[idx] = lo | (hi << 16);
}

// ---------------- K6 v5: per-wave register-resident online softmax, one barrier ----------------
// Each wave owns a disjoint m-partition (16 rows/step x 16 steps); per-lane running
// (mu, ell, acc[12]) for its column n = n0 + ns*16 + c16; quad = m sub-dim.
// Flash-style merge across quads (shfl) and waves (tiny LDS, single __syncthreads).
__global__ __launch_bounds__(256) void k6_spatial(
    const __hip_bfloat16* __restrict__ Qs, const __hip_bfloat16* __restrict__ Ks,
    const uint* __restrict__ pk, const float* __restrict__ x,
    float* __restrict__ rhs) {
  const int b  = blockIdx.x;
  const int k  = blockIdx.y;
  const int n0 = blockIdx.z * 32;
  const ushort* Qb = (const ushort*)(Qs + (size_t)((b * K_ + k) * N_) * 32);
  const ushort* Kb = (const ushort*)(Ks + (size_t)((b * K_ + k) * N_) * 32);
  const uint* pkk = pk + (size_t)k * (N_ * N_);
  const float* xb = x + b * N_ * T_;

  __shared__ float wmu[4][32], well[4][32];
  __shared__ float wacc[4][32][12];

  const int tid  = threadIdx.x;
  const int w    = tid >> 6, lane = tid & 63;
  const int quad = lane >> 4, c16 = lane & 15;

  // K fragments resident in registers (same per-lane values the old LDS path produced)
  bf16x8 bfr0 = *(const bf16x8*)(Kb + (size_t)(n0 + c16) * 32 + quad * 8);
  bf16x8 bfr1 = *(const bf16x8*)(Kb + (size_t)(n0 + 16 + c16) * 32 + quad * 8);

  float mu0 = -1e30f, mu1 = -1e30f, el0 = 0.f, el1 = 0.f;
  float acc0[12], acc1[12];
  #pragma unroll
  for (int t = 0; t < 12; ++t) { acc0[t] = 0.f; acc1[t] = 0.f; }

  for (int s = 0; s < 16; ++s) {
    const int m0 = s * 64 + w * 16;          // this wave's 16-row chunk
    bf16x8 af = *(const bf16x8*)(Qb + (size_t)(m0 + c16) * 32 + quad * 8);
    f32x4 z = {0.f, 0.f, 0.f, 0.f};
    f32x4 sc0 = __builtin_amdgcn_mfma_f32_16x16x32_bf16(af, bfr0, z, 0, 0, 0);
    f32x4 sc1 = __builtin_amdgcn_mfma_f32_16x16x32_bf16(af, bfr1, z, 0, 0, 0);

    const int mrow = m0 + quad * 4;
    float sv0[4], sv1[4], ch0[4], ch1[4];
    #pragma unroll
    for (int r = 0; r < 4; ++r) {
      uint p2 = pkk[(size_t)(mrow + r) * N_ + n0 + c16];
      uint q2 = pkk[(size_t)(mrow + r) * N_ + n0 + 16 + c16];
      sv0[r] = sc0[r] * RSQRT_DK + __uint_as_float(p2 << 16);
      ch0[r] = __uint_as_float(p2 & 0xFFFF0000u);
      sv1[r] = sc1[r] * RSQRT_DK + __uint_as_float(q2 << 16);
      ch1[r] = __uint_as_float(q2 & 0xFFFF0000u);
    }
    // column max for this chunk: own 4 rows, then across quads (no barrier)
    float cm0 = fmaxf(fmaxf(sv0[0], sv0[1]), fmaxf(sv0[2], sv0[3]));
    float cm1 = fmaxf(fmaxf(sv1[0], sv1[1]), fmaxf(sv1[2], sv1[3]));
    cm0 = fmaxf(cm0, __shfl_xor(cm0, 16)); cm0 = fmaxf(cm0, __shfl_xor(cm0, 32));
    cm1 = fmaxf(cm1, __shfl_xor(cm1, 16)); cm1 = fmaxf(cm1, __shfl_xor(cm1, 32));
    float nm0 = fmaxf(mu0, cm0), nm1 = fmaxf(mu1, cm1);
    float f0 = __expf(mu0 - nm0), f1 = __expf(mu1 - nm1);
    mu0 = nm0; mu1 = nm1;
    el0 *= f0; el1 *= f1;
    #pragma unroll
    for (int t = 0; t < 12; ++t) { acc0[t] *= f0; acc1[t] *= f1; }

    float p0[4], p1[4];
    #pragma unroll
    for (int r = 0; r < 4; ++r) {
      p0[r] = __expf(sv0[r] - mu0); el0 += p0[r]; p0[r] *= ch0[r];
      p1[r] = __expf(sv1[r] - mu1); el1 += p1[r]; p1[r] *= ch1[r];
    }
    // PV: quad-uniform broadcast reads of x rows (L2-hit), FMA into registers
    #pragma unroll
    for (int r = 0; r < 4; ++r) {
      const float4* xr = (const float4*)(xb + (size_t)(mrow + r) * 12);
      float4 xA = xr[0], xB = xr[1], xC = xr[2];
      float xv[12] = {xA.x, xA.y, xA.z, xA.w, xB.x, xB.y, xB.z, xB.w,
                      xC.x, xC.y, xC.z, xC.w};
      float px0 = p0[r], px1 = p1[r];
      #pragma unroll
      for (int t = 0; t < 12; ++t) {
        acc0[t] = fmaf(px0, xv[t], acc0[t]);
        acc1[t] = fmaf(px1, xv[t], acc1[t]);
      }
    }
  }

  // reduce ell/acc across quads (mu already quad-uniform)
  #pragma unroll
  for (int off = 16; off <= 32; off <<= 1) {
    el0 += __shfl_xor(el0, off);
    el1 += __shfl_xor(el1, off);
    #pragma unroll
    for (int t = 0; t < 12; ++t) {
      acc0[t] += __shfl_xor(acc0[t], off);
      acc1[t] += __shfl_xor(acc1[t], off);
    }
  }
  if (quad == 0) {
    wmu[w][c16] = mu0; well[w][c16] = el0;
    #pragma unroll
    for (int t = 0; t < 12; ++t) wacc[w][c16][t] = acc0[t];
  } else if (quad == 1) {
    wmu[w][16 + c16] = mu1; well[w][16 + c16] = el1;
    #pragma unroll
    for (int t = 0; t < 12; ++t) wacc[w][16 + c16][t] = acc1[t];
  }
  __syncthreads();
  // merge the 4 wave-partitions (flash merge) and write out
  if (tid < 384) {
    int n = tid / 12, t = tid - n * 12;
    float m0v = wmu[0][n], m1v = wmu[1][n], m2v = wmu[2][n], m3v = wmu[3][n];
    float gm = fmaxf(fmaxf(m0v, m1v), fmaxf(m2v, m3v));
    float e0 = __expf(m0v - gm), e1 = __expf(m1v - gm);
    float e2 = __expf(m2v - gm), e3 = __expf(m3v - gm);
    float den = well[0][n] * e0 + well[1][n] * e1 + well[2][n] * e2 + well[3][n] * e3;
    float num = wacc[0][n][t] * e0 + wacc[1][n][t] * e1 +
                wacc[2][n][t] * e2 + wacc[3][n][t] * e3;
    rhs[((size_t)(b * K_ + k) * N_ + n0 + n) * 12 + t] = num / den;
  }
}

// ---------------- K8 v3 (MFMA): Theta+relu -> GTU convs (MFMA) -> fcmy -> residual+LN ----------------
// tc_h is XOR-swizzled: bank was (cc&1)*16 + j/2 for ALL 64 lanes (64-way conflict,
// ~1.7e7 conflict cycles). idx ^ ((s&15)<<1) spreads s across 16 banks -> 4-way.
template<int KS, int JV, int JB>
__device__ __forceinline__ void conv_mfma(const ushort* X_th, const ushort* wl_h,
                                          ushort* tc_h, const float* bias0,
                                          int mp, int ntg, int quad, int c16) {
  f32x4 accA[3], accB[3];
  #pragma unroll
  for (int i = 0; i < 3; ++i) { accA[i] = (f32x4){0.f,0.f,0.f,0.f}; accB[i] = (f32x4){0.f,0.f,0.f,0.f}; }
  #pragma unroll
  for (int dt = 0; dt < KS; ++dt) {
    bf16x8 A0 = *(const bf16x8*)&wl_h[dt * 2560 + (mp * 16 + c16) * 40 + quad * 8];
    bf16x8 A1 = *(const bf16x8*)&wl_h[dt * 2560 + ((mp + 2) * 16 + c16) * 40 + quad * 8];
    #pragma unroll
    for (int i = 0; i < 3; ++i) {
      int nt = ntg * 3 + i;
      int j = nt >> 1, sh = nt & 1;
      bf16x8 Bf = *(const bf16x8*)&X_th[(sh * 16 + c16) * 584 + (j + dt) * 32 + quad * 8];
      accA[i] = __builtin_amdgcn_mfma_f32_16x16x32_bf16(A0, Bf, accA[i], 0, 0, 0);
      accB[i] = __builtin_amdgcn_mfma_f32_16x16x32_bf16(A1, Bf, accB[i], 0, 0, 0);
    }
  }
  #pragma unroll
  for (int i = 0; i < 3; ++i) {
    int nt = ntg * 3 + i, j = nt >> 1, sh = nt & 1;
    if (j < JV) {
      int s = sh * 16 + c16;
      int sx = (s & 15) << 1;
      #pragma unroll
      for (int r = 0; r < 4; ++r) {
        int cc = mp * 16 + quad * 4 + r;
        float a = accA[i][r] + bias0[cc];
        float g = accB[i][r] + bias0[cc + 32];
        float e2a = __expf(2.f * a);
        float th = 1.f - 2.f / (e2a + 1.f);
        float sg = 1.f / (1.f + __expf(-g));
        tc_h[((s * 32 + cc) * 32 + (JB + j)) ^ sx] = f2bf(th * sg);
      }
    }
  }
}

__global__ __launch_bounds__(1024) void k8_fused(
                       const float* __restrict__ rhs, const float* __restrict__ Theta,
                       const float* __restrict__ x, const float* __restrict__ rw,
                       const float* __restrict__ rb,
                       const float* __restrict__ w3, const float* __restrict__ b3,
                       const float* __restrict__ w5, const float* __restrict__ b5,
                       const float* __restrict__ w7, const float* __restrict__ b7,
                       const float* __restrict__ fw, const float* __restrict__ fb,
                       const float* __restrict__ gf, const float* __restrict__ bf,
                       float* __restrict__ out) {
  int bn0 = blockIdx.x * 32;
  int b = bn0 >> 10, n0 = bn0 & 1023;

  __shared__ __align__(16) char uR[73216];
  ushort* X_th = (ushort*)uR;                 // [32 s][18 t][32 ic], site stride 584 shorts
  ushort* wl_h = (ushort*)(uR + 37376);       // [dt][64 co][40], dt stride 2560 shorts
  float*  v_l  = (float*)uR;                  // [32][391] (odd stride: bank spread)
  __shared__ __align__(16) ushort tc_h[1024 * 32];
  __shared__ float rhs_l[32 * 36];
  __shared__ float Th_l[96];
  __shared__ float xr_l[32 * 12];
  __shared__ float fw_l[288];
  __shared__ float fb_l[12];
  __shared__ float bias_l[3][64];
  __shared__ float rw_l[32], rb_l[32], gf_l[32], bf_l[32];
  __shared__ float stm[384], str[384];

  int tid = threadIdx.x;
  int w = tid >> 6, lane = tid & 63, quad = lane >> 4, c16 = lane & 15;
  int mp = w & 1, ntg = w >> 1;
  int c = (tid >> 3) & 31;
  int site = (tid & 7) | ((tid >> 8) << 3);

  for (int idx = tid; idx < 1152; idx += 1024) {
    int s = idx / 36, r = idx - s * 36, k = r / 12, t = r - k * 12;
    rhs_l[idx] = rhs[((size_t)(b * 3 + k) * N_ + n0 + s) * 12 + t];
  }
  if (tid < 384) xr_l[tid] = x[(size_t)(b * N_ + n0) * 12 + tid];
  if (tid < 96) Th_l[tid] = Theta[tid];
  if (tid < 288) fw_l[tid] = fw[tid];
  if (tid < 12) fb_l[tid] = fb[tid];
  if (tid < 64) { bias_l[0][tid] = b3[tid]; bias_l[1][tid] = b5[tid]; bias_l[2][tid] = b7[tid]; }
  if (tid >= 64 && tid < 96)  rw_l[tid - 64] = rw[tid - 64];
  if (tid >= 96 && tid < 128) rb_l[tid - 96] = rb[tid - 96];
  if (tid >= 128 && tid < 160) gf_l[tid - 128] = gf[tid - 128];
  if (tid >= 160 && tid < 192) bf_l[tid - 160] = bf[tid - 160];
  for (int idx = tid; idx < 64 * 32 * 3; idx += 1024) {
    int co = idx / 96, r2 = idx - co * 96, ic = r2 / 3, dt = r2 - ic * 3;
    wl_h[dt * 2560 + co * 40 + ic] = f2bf(w3[idx]);
  }
  __syncthreads();

  {
    float th0 = Th_l[c], th1 = Th_l[32 + c], th2 = Th_l[64 + c];
    const float* rs_ = &rhs_l[site * 36];
    ushort* xo = &X_th[site * 584 + c];
    #pragma unroll
    for (int t = 0; t < 12; ++t) {
      float a = rs_[t] * th0 + rs_[12 + t] * th1 + rs_[24 + t] * th2;
      xo[t * 32] = f2bf(fmaxf(a, 0.f));
    }
  }
  for (int idx = tid; idx < 32 * 6 * 32; idx += 1024) {
    int s = idx / 192, r2 = idx - s * 192, tt = r2 >> 5, ic = r2 & 31;
    X_th[s * 584 + (12 + tt) * 32 + ic] = 0;
  }
  __syncthreads();

  conv_mfma<3, 10, 0>(X_th, wl_h, tc_h, &bias_l[0][0], mp, ntg, quad, c16);
  __syncthreads();
  for (int idx = tid; idx < 64 * 32 * 5; idx += 1024) {
    int co = idx / 160, r2 = idx - co * 160, ic = r2 / 5, dt = r2 - ic * 5;
    wl_h[dt * 2560 + co * 40 + ic] = f2bf(w5[idx]);
  }
  __syncthreads();
  conv_mfma<5, 8, 10>(X_th, wl_h, tc_h, &bias_l[1][0], mp, ntg, quad, c16);
  __syncthreads();
  for (int idx = tid; idx < 64 * 32 * 7; idx += 1024) {
    int co = idx / 224, r2 = idx - co * 224, ic = r2 / 7, dt = r2 - ic * 7;
    wl_h[dt * 2560 + co * 40 + ic] = f2bf(w7[idx]);
  }
  __syncthreads();
  conv_mfma<7, 6, 18>(X_th, wl_h, tc_h, &bias_l[2][0], mp, ntg, quad, c16);
  __syncthreads();

  float tcv[24];
  {
    int rb2 = (site * 32 + c) * 32;
    int sx = (site & 15) << 1;
    #pragma unroll
    for (int j = 0; j < 24; ++j)
      tcv[j] = __uint_as_float(((uint)tc_h[(rb2 + j) ^ sx]) << 16);
  }
  float o[12];
  #pragma unroll
  for (int t = 0; t < 12; ++t) o[t] = fb_l[t];
  #pragma unroll
  for (int j = 0; j < 24; ++j) {
    const float4* fp = (const float4*)&fw_l[j * 12];
    float4 f0 = fp[0], f1 = fp[1], f2 = fp[2];
    float fr[12] = {f0.x, f0.y, f0.z, f0.w, f1.x, f1.y, f1.z, f1.w, f2.x, f2.y, f2.z, f2.w};
    #pragma unroll
    for (int t = 0; t < 12; ++t) o[t] = fmaf(tcv[j], fr[t], o[t]);
  }

  float v[12];
  {
    float rwc = rw_l[c], rbc = rb_l[c];
    const float* xs = &xr_l[site * 12];
    float* vo = &v_l[site * 391 + c * 12];
    #pragma unroll
    for (int t = 0; t < 12; ++t) {
      float xres = xs[t] * rwc + rbc;
      v[t] = fmaxf(xres + fmaxf(o[t], 0.f), 0.f);
      vo[t] = v[t];
    }
  }
  __syncthreads();
  if (tid < 384) {
    int s = tid / 12, t = tid - s * 12;
    float sm = 0.f, s2 = 0.f;
    #pragma unroll 8
    for (int cc = 0; cc < 32; ++cc) {
      float u = v_l[s * 391 + cc * 12 + t];
      sm += u; s2 += u * u;
    }
    float m = sm * (1.f / 32.f);
    stm[tid] = m;
    str[tid] = rsqrtf(s2 * (1.f / 32.f) - m * m + 1e-5f);
  }
  __syncthreads();
  {
    float gfc = gf_l[c], bfc = bf_l[c];
    const float* sm_ = &stm[site * 12];
    const float* sr_ = &str[site * 12];
    float q[12];
    #pragma unroll
    for (int t = 0; t < 12; ++t) q[t] = (v[t] - sm_[t]) * sr_[t] * gfc + bfc;
    float* op = &out[(size_t)(bn0 + site) * 384 + c * 12];
    ((float4*)op)[0] = make_float4(q[0], q[1], q[2], q[3]);
    ((float4*)op)[1] = make_float4(q[4], q[5], q[6], q[7]);
    ((float4*)op)[2] = make_float4(q[8], q[9], q[10], q[11]);
  }
}

// ---------------- launch ----------------
extern "C" void kernel_launch(void* const* d_in, const int* in_sizes, int n_in,
                              void* d_out, int out_size, void* d_ws, size_t ws_size,
                              hipStream_t stream) {
  const float* x       = (const float*)d_in[0];
  const float* res_att = (const float*)d_in[1];
  const float* posT    = (const float*)d_in[2];
  const float* gT      = (const float*)d_in[3];
  const float* bT      = (const float*)d_in[4];
  const float* WQt     = (const float*)d_in[5];
  const float* WKt     = (const float*)d_in[6];
  const float* WVt     = (const float*)d_in[7];
  const float* fct     = (const float*)d_in[8];
  const float* pcw     = (const float*)d_in[9];
  const float* pcb     = (const float*)d_in[10];
  const float* posS    = (const float*)d_in[11];
  const float* gS      = (const float*)d_in[12];
  const float* bS      = (const float*)d_in[13];
  const float* WQs     = (const float*)d_in[14];
  const float* WKs     = (const float*)d_in[15];
  const float* cheb    = (const float*)d_in[16];
  const float* adj     = (const float*)d_in[17];
  const float* mask    = (const float*)d_in[18];
  const float* Theta   = (const float*)d_in[19];
  const float* w3      = (const float*)d_in[20];
  const float* b3      = (const float*)d_in[21];
  const float* w5      = (const float*)d_in[22];
  const float* b5      = (const float*)d_in[23];
  const float* w7      = (const float*)d_in[24];
  const float* b7      = (const float*)d_in[25];
  const float* rw      = (const float*)d_in[26];
  const float* rb      = (const float*)d_in[27];
  const float* fw      = (const float*)d_in[28];
  const float* fb      = (const float*)d_in[29];
  const float* gf      = (const float*)d_in[30];
  const float* bf      = (const float*)d_in[31];

  float* ws = (float*)d_ws;
  float* TEmx = ws;                         // 196608
  float* qkv  = TEmx + 196608;              // 55296 (unused)
  float* ctx  = qkv + 55296;                // 18432
  float* TAT  = ctx + 18432;                // 196608
  float* SEmx = TAT + 196608;               // 8388608 (reused: part pre-k4, pk during k6)
  float* Qsf  = SEmx + 8388608;             // 1572864 slots (bf16 uses half)
  float* Ksf  = Qsf + 1572864;              // 1572864
  float* rhs  = Ksf + 1572864;              // 589824
  ushort* wpre = (ushort*)(rhs + 589824);   // 98304 shorts (former tco slot)
  float* part = SEmx;                       // overlay: k2 partials, dead before k4

  __hip_bfloat16* Qh = (__hip_bfloat16*)Qsf;
  __hip_bfloat16* Kh = (__hip_bfloat16*)Ksf;
  uint* pk = (uint*)SEmx;                   // 3M uints = 12 MB, dead after k6

  float* out  = (float*)d_out;
  float* reAt = out + 6291456;

  k5_pre<<<(DM_ * 192) / 256, 256, 0, stream>>>(WQs, WKs, wpre);
  k1_temporal_ln<<<B_ * T_, 256, 0, stream>>>(x, posT, gT, bT, TEmx);
  k2_qkv<<<dim3(4, B_ * T_), 256, 0, stream>>>(TEmx, WQt, WKt, WVt, part);
  k3a_attn<<<B_, 256, 0, stream>>>(part, res_att, reAt, ctx);
  k3b_tat<<<B_ * T_, 1024, 0, stream>>>(ctx, fct, TEmx, TAT);
  k4_preconv_ln<<<B_ * N_, 256, 0, stream>>>(TAT, pcw, pcb, posS, gS, bS, SEmx);
  k5_qks<<<dim3(N_ / 32, B_), 256, 0, stream>>>(SEmx, wpre, Qh, Kh);
  k6_pre<<<(K_ * N_ * N_) / 256, 256, 0, stream>>>(adj, mask, cheb, pk);
  k6_spatial<<<dim3(B_, K_, N_ / 32), 256, 0, stream>>>(Qh, Kh, pk, x, rhs);
  k8_fused<<<B_ * N_ / 32, 1024, 0, stream>>>(rhs, Theta, x, rw, rb,
                                              w3, b3, w5, b5, w7, b7, fw, fb, gf, bf, out);
}